// Round 5
// baseline (3397.540 us; speedup 1.0000x reference)
//
#include <hip/hip_runtime.h>

#define NB 4
#define NH 8
#define SS 2048
#define DD 64
#define QT 64
#define KT 64
#define KS 72   // LDS row stride (elements); 144 B = multiple of 16 B (b128-aligned)

typedef float  f32x4  __attribute__((ext_vector_type(4)));
typedef short  s16x8  __attribute__((ext_vector_type(8)));
typedef __bf16 b16x8  __attribute__((ext_vector_type(8)));

__device__ __forceinline__ unsigned short f2bf(float x) {
  unsigned u = __builtin_bit_cast(unsigned, x);
  u += 0x7fffu + ((u >> 16) & 1u);
  return (unsigned short)(u >> 16);
}
__device__ __forceinline__ float bf2f(unsigned short h) {
  unsigned u = ((unsigned)h) << 16;
  return __builtin_bit_cast(float, u);
}

// SFINAE hedge: builtin may want <8 x i16> or <8 x bfloat>.
template <typename T>
__device__ __forceinline__ auto mfma16x16x32_bf16(T a, T b, f32x4 c, int)
    -> decltype(__builtin_amdgcn_mfma_f32_16x16x32_bf16(a, b, c, 0, 0, 0)) {
  return __builtin_amdgcn_mfma_f32_16x16x32_bf16(a, b, c, 0, 0, 0);
}
template <typename T>
__device__ __forceinline__ f32x4 mfma16x16x32_bf16(T a, T b, f32x4 c, long) {
  b16x8 a2 = __builtin_bit_cast(b16x8, a);
  b16x8 b2 = __builtin_bit_cast(b16x8, b);
  return __builtin_amdgcn_mfma_f32_16x16x32_bf16(a2, b2, c, 0, 0, 0);
}
__device__ __forceinline__ f32x4 MFMA(s16x8 a, s16x8 b, f32x4 c) {
  return mfma16x16x32_bf16(a, b, c, 0);
}

__global__ __launch_bounds__(256) void attn_fused(
    const float* __restrict__ Qp, const float* __restrict__ Kp,
    const float* __restrict__ Vp, const unsigned char* __restrict__ Mp,
    const float* __restrict__ Ep, float* __restrict__ outC,
    float* __restrict__ outA, float* __restrict__ outS) {
  __shared__ unsigned short KHI[KT][KS];
  __shared__ unsigned short KLO[KT][KS];
  __shared__ unsigned short VT[DD][KS];        // V transposed: VT[d][k_local]
  __shared__ unsigned short PB[4][16][KS];     // per-wave P bounce buffer
  __shared__ unsigned short PM[4][16][128];    // packed mask bits: [wave][row][k>>4]

  const int gid = blockIdx.x;
  const int qt = gid & 31, bh = gid >> 5, b = bh >> 3;
  const int tid = threadIdx.x, w = tid >> 6, l = tid & 63;
  const int lr = l & 15, lg = l >> 4;
  const int qr0 = qt * QT + w * 16;
  const int rowq = lg * 4;  // + reg -> row within wave's 16-row strip

  // ---- detect mask storage: int32 bools (first 64 words all <=1) vs byte bools
  const unsigned* Mu = (const unsigned*)Mp;
  int allle1 = 1;
#pragma unroll 1
  for (int i = 0; i < 64; ++i) allle1 &= (Mu[i] <= 1u);
  const int msh = allle1 ? 2 : 0;  // byte index = element index << msh

  const float* Kbh = Kp + (size_t)bh * SS * DD;
  const float* Vbh = Vp + (size_t)bh * SS * DD;
  const unsigned char* Mbh = Mp + (((size_t)bh * SS * SS) << msh);
  const float* Eb = Ep + (size_t)b * SS * SS;
  float* outSbh = outS + (size_t)bh * SS * SS;
  float* outAbh = outA + (size_t)bh * SS * SS;

  // ---- Q fragments (bf16 hi/lo split). A-frag: row = lane&15, k = (lane>>4)*8 + j
  s16x8 qhi[2], qlo[2];
  {
    const float* qp = Qp + ((size_t)bh * SS + qr0 + lr) * DD + lg * 8;
#pragma unroll
    for (int st = 0; st < 2; ++st) {
#pragma unroll
      for (int j = 0; j < 8; ++j) {
        float x = qp[st * 32 + j];
        unsigned short h = f2bf(x);
        float lo = x - bf2f(h);
        qhi[st][j] = (short)h;
        qlo[st][j] = (short)f2bf(lo);
      }
    }
  }

  float mrow[4], lrow[4];
#pragma unroll
  for (int r = 0; r < 4; ++r) { mrow[r] = -__builtin_inff(); lrow[r] = 0.f; }

  auto stageK = [&](int k0) {
#pragma unroll
    for (int rep = 0; rep < 4; ++rep) {
      int idx = (rep * 256 + tid) * 4;
      int kr = idx >> 6, c = idx & 63;
      const float4 v = *(const float4*)(Kbh + (size_t)(k0 + kr) * DD + c);
      unsigned short h0 = f2bf(v.x), h1 = f2bf(v.y), h2 = f2bf(v.z), h3 = f2bf(v.w);
      *(ushort4*)&KHI[kr][c] = make_ushort4(h0, h1, h2, h3);
      *(ushort4*)&KLO[kr][c] = make_ushort4(f2bf(v.x - bf2f(h0)), f2bf(v.y - bf2f(h1)),
                                            f2bf(v.z - bf2f(h2)), f2bf(v.w - bf2f(h3)));
    }
  };
  auto stageV = [&](int k0) {
#pragma unroll
    for (int rep = 0; rep < 4; ++rep) {
      int idx = (rep * 256 + tid) * 4;
      int kr = idx >> 6, c = idx & 63;
      const float4 v = *(const float4*)(Vbh + (size_t)(k0 + kr) * DD + c);
      VT[c + 0][kr] = f2bf(v.x);
      VT[c + 1][kr] = f2bf(v.y);
      VT[c + 2][kr] = f2bf(v.z);
      VT[c + 3][kr] = f2bf(v.w);
    }
  };

  // raw QK^T accumulators for this wave's 16x64 strip.
  // C layout: row=(lane>>4)*4+reg, col=lane&15
  auto computeQK = [&](float raw[4][4]) {
#pragma unroll
    for (int nt = 0; nt < 4; ++nt) {
      f32x4 a = {0.f, 0.f, 0.f, 0.f};
#pragma unroll
      for (int st = 0; st < 2; ++st) {
        s16x8 kh = *(const s16x8*)&KHI[nt * 16 + lr][st * 32 + lg * 8];
        s16x8 kl = *(const s16x8*)&KLO[nt * 16 + lr][st * 32 + lg * 8];
        a = MFMA(qhi[st], kh, a);
        a = MFMA(qlo[st], kh, a);
        a = MFMA(qhi[st], kl, a);
      }
#pragma unroll
      for (int reg = 0; reg < 4; ++reg) raw[nt][reg] = a[reg];
    }
  };

  // ================= Pass A: scores + packed mask + online (m, l) =================
  for (int kt = 0; kt < 32; ++kt) {
    const int k0 = kt * KT;
    __syncthreads();
    stageK(k0);
    __syncthreads();
    float raw[4][4];
    computeQK(raw);
    float sv[4][4];
#pragma unroll
    for (int nt = 0; nt < 4; ++nt) {
#pragma unroll
      for (int reg = 0; reg < 4; ++reg) {
        const int q = qr0 + rowq + reg;
        const int k = k0 + nt * 16 + lr;
        const size_t off = (size_t)q * SS + k;
        const unsigned char mk = Mbh[off << msh];
        unsigned long long bal = __ballot(mk != 0);
        if (lr == 0) PM[w][rowq + reg][kt * 4 + nt] = (unsigned short)(bal >> (lg * 16));
        const float e = Eb[off];
        const float s = mk ? -1e9f : fmaf(raw[nt][reg], 0.125f, e);
        sv[nt][reg] = s;
        outSbh[off] = s;
      }
    }
#pragma unroll
    for (int reg = 0; reg < 4; ++reg) {
      float tm = fmaxf(fmaxf(sv[0][reg], sv[1][reg]), fmaxf(sv[2][reg], sv[3][reg]));
      tm = fmaxf(tm, __shfl_xor(tm, 1));
      tm = fmaxf(tm, __shfl_xor(tm, 2));
      tm = fmaxf(tm, __shfl_xor(tm, 4));
      tm = fmaxf(tm, __shfl_xor(tm, 8));
      const float mn = fmaxf(mrow[reg], tm);
      float ps = __expf(sv[0][reg] - mn) + __expf(sv[1][reg] - mn) +
                 __expf(sv[2][reg] - mn) + __expf(sv[3][reg] - mn);
      ps += __shfl_xor(ps, 1);
      ps += __shfl_xor(ps, 2);
      ps += __shfl_xor(ps, 4);
      ps += __shfl_xor(ps, 8);
      lrow[reg] = lrow[reg] * __expf(mrow[reg] - mn) + ps;
      mrow[reg] = mn;
    }
  }

  float rl[4];
#pragma unroll
  for (int r = 0; r < 4; ++r) rl[r] = 1.0f / lrow[r];

  f32x4 ctx[4];
#pragma unroll
  for (int dt = 0; dt < 4; ++dt) ctx[dt] = (f32x4){0.f, 0.f, 0.f, 0.f};

  // ================= Pass B: recompute scores -> attn + context =================
  for (int kt = 0; kt < 32; ++kt) {
    const int k0 = kt * KT;
    __syncthreads();
    stageK(k0);
    stageV(k0);
    __syncthreads();
    float raw[4][4];
    computeQK(raw);
#pragma unroll
    for (int nt = 0; nt < 4; ++nt) {
#pragma unroll
      for (int reg = 0; reg < 4; ++reg) {
        const int q = qr0 + rowq + reg;
        const int k = k0 + nt * 16 + lr;
        const size_t off = (size_t)q * SS + k;
        const unsigned short pmw = PM[w][rowq + reg][kt * 4 + nt];
        const int mk = (pmw >> lr) & 1;
        const float e = Eb[off];
        const float s = fmaf(raw[nt][reg], 0.125f, e);
        const float p = mk ? 0.f : __expf(s - mrow[reg]) * rl[reg];
        outAbh[off] = p;
        PB[w][rowq + reg][nt * 16 + lr] = f2bf(p);
      }
    }
    // P·V  (A = P: row=lane&15, k=(lane>>4)*8+j ; B = V^T: col d = lane&15)
#pragma unroll
    for (int st = 0; st < 2; ++st) {
      s16x8 pa = *(const s16x8*)&PB[w][lr][st * 32 + lg * 8];
#pragma unroll
      for (int dt = 0; dt < 4; ++dt) {
        s16x8 vb = *(const s16x8*)&VT[dt * 16 + lr][st * 32 + lg * 8];
        ctx[dt] = MFMA(pa, vb, ctx[dt]);
      }
    }
  }

#pragma unroll
  for (int dt = 0; dt < 4; ++dt)
#pragma unroll
    for (int reg = 0; reg < 4; ++reg)
      outC[((size_t)bh * SS + qr0 + rowq + reg) * DD + dt * 16 + lr] = ctx[dt][reg];
}

extern "C" void kernel_launch(void* const* d_in, const int* in_sizes, int n_in,
                              void* d_out, int out_size, void* d_ws, size_t ws_size,
                              hipStream_t stream) {
  (void)in_sizes; (void)n_in; (void)d_ws; (void)ws_size; (void)out_size;
  const float* Q = (const float*)d_in[0];
  const float* K = (const float*)d_in[1];
  const float* V = (const float*)d_in[2];
  const unsigned char* M = (const unsigned char*)d_in[3];
  const float* E = (const float*)d_in[4];
  float* outC = (float*)d_out;
  float* outA = outC + (size_t)NB * NH * SS * DD;
  float* outS = outA + (size_t)NB * NH * SS * SS;
  dim3 grid(NB * NH * (SS / QT));
  attn_fused<<<grid, dim3(256), 0, stream>>>(Q, K, V, M, E, outC, outA, outS);
}